// Round 14
// baseline (17.721 us; speedup 1.0000x reference)
//
#include <hip/hip_runtime.h>

#define HWD    48400          // 220*220
#define PATCHD 75
#define NPOS   96800          // 2 * HWD
#define XBAT   3630000        // PATCHD * HWD
#define LOG2E  1.44269504088896340736f

typedef __attribute__((ext_vector_type(8))) _Float16 f16x8;
typedef __attribute__((ext_vector_type(2))) __fp16   h16x2;   // cvt_pkrtz return type
typedef __attribute__((ext_vector_type(4))) float    f32x4;

union U2 { h16x2 h; unsigned u; };
union UF { unsigned u[4]; f16x8 v; };

#define GLOAD_LDS16(gp, lp) __builtin_amdgcn_global_load_lds(             \
    (const __attribute__((address_space(1))) void*)(gp),                  \
    (__attribute__((address_space(3))) void*)(lp), 16, 0, 0)

// ---------------------------------------------------------------------------
// Table build, FRAGMENT-MAJOR layout (unchanged from round 10):
//   tbl[((t*4 + g)*16 + c)*8 + j],  t = role*3 + s,  k = 32s + 8g + j
//   role 0 = exp(k1), 1 = k1*exp(k1), 2 = exp(k2), 3 = k2*exp(k2); k>=75 -> 0
// ---------------------------------------------------------------------------
__global__ void smorph_build_tables(const float* __restrict__ k1,
                                    const float* __restrict__ k2,
                                    _Float16* __restrict__ tbl)
{
    int i = (int)blockIdx.x * 256 + (int)threadIdx.x;   // 6144 entries
    if (i >= 4 * 3 * 4 * 16 * 8) return;
    const int j = i & 7;
    const int c = (i >> 3) & 15;
    const int g = (i >> 7) & 3;
    const int t = i >> 9;          // 0..11 = role*3 + s
    const int s = t % 3;
    const int r = t / 3;
    const int k = 32 * s + 8 * g + j;
    float val = 0.f;
    if (k < PATCHD) {
        const float* kw = (r < 2) ? k1 : k2;
        const float w = kw[k * 16 + c];
        const float e = __expf(w);
        val = (r & 1) ? (w * e) : e;
    }
    tbl[i] = (_Float16)val;
}

// ---------------------------------------------------------------------------
// Main: block = 128 positions, 4 waves x 2 MFMA tiles. x staged via
// global_load_lds with ALL 64 lanes distinct (2 k-rows x 512B contiguous per
// instr), double-buffered [32][128] LDS. Output gathered in LDS and stored as
// 512B-contiguous float4 rows. DRAM sees >=512B strips instead of 64B grains.
// ---------------------------------------------------------------------------
__global__ __launch_bounds__(256, 3)
void smorph_mfma9(const float* __restrict__ x,
                  const _Float16* __restrict__ tbl,
                  const float* __restrict__ bias,
                  float* __restrict__ out)
{
    __shared__ __align__(16) float sX[2][32][128];   // 2 x 16 KB

    const int tid = (int)threadIdx.x;
    const int l   = tid & 63;
    const int w   = tid >> 6;
    const int g   = l >> 4;         // k-subgroup 0..3
    const int c   = l & 15;         // channel lane (A-op) / position lane (B-op, D)

    int pbase = (int)blockIdx.x * 128;
    if (pbase > NPOS - 128) pbase = NPOS - 128;      // clamp: duplicate identical stores

    // ---- table fragments -> registers (12 coalesced dwordx4, L2-hot) ----
    const f16x8* tf = (const f16x8*)tbl;
    const int fbase = g * 16 + c;
    f16x8 Tf[12];
    #pragma unroll
    for (int t = 0; t < 12; ++t) Tf[t] = tf[t * 64 + fbase];

    // ---- staging lane geometry: lane covers 16B of row (w*8+2i+lhi) ----
    const int lhi = l >> 5;                          // which of the 2 rows
    const int llo = l & 31;                          // 512B strip offset /16
    const int ps  = pbase + 4 * llo;                 // lane's 4-float position base
    const int sb  = (ps >= HWD) ? 1 : 0;             // per-lane batch (16B never straddles)
    const float* sgb = x + (size_t)sb * XBAT + (ps - sb * HWD);

    #define STAGE(buf, s)                                                     \
        {                                                                     \
            _Pragma("unroll")                                                 \
            for (int i_ = 0; i_ < 4; ++i_) {                                  \
                const int kg_ = 32 * (s) + w * 8 + 2 * i_ + lhi;              \
                if (kg_ < PATCHD)                                             \
                    GLOAD_LDS16(sgb + (size_t)kg_ * HWD,                      \
                                &sX[buf][w * 8 + 2 * i_][0]);                 \
            }                                                                 \
        }

    f32x4 aN1A = {0.f,0.f,0.f,0.f}, aD1A = {0.f,0.f,0.f,0.f};
    f32x4 aN2A = {0.f,0.f,0.f,0.f}, aD2A = {0.f,0.f,0.f,0.f};
    f32x4 aN1B = {0.f,0.f,0.f,0.f}, aD1B = {0.f,0.f,0.f,0.f};
    f32x4 aN2B = {0.f,0.f,0.f,0.f}, aD2B = {0.f,0.f,0.f,0.f};

    #define COMP(buf, s, T, aN1, aD1, aN2, aD2)                               \
        {                                                                     \
            float xv[8];                                                      \
            _Pragma("unroll")                                                 \
            for (int j_ = 0; j_ < 8; ++j_) {                                  \
                float v_ = sX[buf][8 * g + j_][w * 32 + (T) * 16 + c];        \
                if ((s) == 2 && (8 * g + j_ >= PATCHD - 64)) v_ = 0.f;        \
                xv[j_] = v_;                                                  \
            }                                                                 \
            float E[8], R[8];                                                 \
            _Pragma("unroll")                                                 \
            for (int j_ = 0; j_ < 8; ++j_) {                                  \
                const float t_ = xv[j_] * LOG2E;                              \
                E[j_] = __builtin_amdgcn_exp2f(t_);                           \
                R[j_] = __builtin_amdgcn_exp2f(-t_);                          \
            }                                                                 \
            UF fEx, fE, fRx, fR;                                              \
            _Pragma("unroll")                                                 \
            for (int jp = 0; jp < 4; ++jp) {                                  \
                const float x0 = xv[2*jp], x1 = xv[2*jp+1];                   \
                U2 q;                                                         \
                q.h = __builtin_amdgcn_cvt_pkrtz(E[2*jp] * x0,  E[2*jp+1] * x1);  fEx.u[jp] = q.u; \
                q.h = __builtin_amdgcn_cvt_pkrtz(E[2*jp],       E[2*jp+1]);       fE.u[jp]  = q.u; \
                q.h = __builtin_amdgcn_cvt_pkrtz(-R[2*jp] * x0, -R[2*jp+1] * x1); fRx.u[jp] = q.u; \
                q.h = __builtin_amdgcn_cvt_pkrtz(R[2*jp],       R[2*jp+1]);       fR.u[jp]  = q.u; \
            }                                                                 \
            aN1 = __builtin_amdgcn_mfma_f32_16x16x32_f16(Tf[0 + (s)], fEx.v, aN1, 0, 0, 0); \
            aN1 = __builtin_amdgcn_mfma_f32_16x16x32_f16(Tf[3 + (s)], fE.v,  aN1, 0, 0, 0); \
            aD1 = __builtin_amdgcn_mfma_f32_16x16x32_f16(Tf[0 + (s)], fE.v,  aD1, 0, 0, 0); \
            aN2 = __builtin_amdgcn_mfma_f32_16x16x32_f16(Tf[6 + (s)], fRx.v, aN2, 0, 0, 0); \
            aN2 = __builtin_amdgcn_mfma_f32_16x16x32_f16(Tf[9 + (s)], fR.v,  aN2, 0, 0, 0); \
            aD2 = __builtin_amdgcn_mfma_f32_16x16x32_f16(Tf[6 + (s)], fR.v,  aD2, 0, 0, 0); \
        }

    // ---- 3-step double-buffered pipeline (no early exits; all waves sync) ----
    STAGE(0, 0);
    __syncthreads();
    STAGE(1, 1);
    COMP(0, 0, 0, aN1A, aD1A, aN2A, aD2A);
    COMP(0, 0, 1, aN1B, aD1B, aN2B, aD2B);
    __syncthreads();
    STAGE(0, 2);
    COMP(1, 1, 0, aN1A, aD1A, aN2A, aD2A);
    COMP(1, 1, 1, aN1B, aD1B, aN2B, aD2B);
    __syncthreads();
    COMP(0, 2, 0, aN1A, aD1A, aN2A, aD2A);
    COMP(0, 2, 1, aN1B, aD1B, aN2B, aD2B);
    #undef STAGE
    #undef COMP

    // ---- epilogue: y -> LDS gather (buf1 is free past barrier 3) ----
    const float4 bsv = *(const float4*)(bias + 4 * g);
    float (*sY)[128] = (float (*)[128])&sX[1][0][0];   // 16 ch x 128 pos = 8 KB
    #pragma unroll
    for (int r = 0; r < 4; ++r) {
        const float bsr = (r == 0) ? bsv.x : (r == 1) ? bsv.y : (r == 2) ? bsv.z : bsv.w;
        const float yA = aN1A[r] * __builtin_amdgcn_rcpf(aD1A[r])
                       + aN2A[r] * __builtin_amdgcn_rcpf(aD2A[r]) + bsr;
        const float yB = aN1B[r] * __builtin_amdgcn_rcpf(aD1B[r])
                       + aN2B[r] * __builtin_amdgcn_rcpf(aD2B[r]) + bsr;
        sY[4 * g + r][w * 32 + 0 * 16 + c] = yA;
        sY[4 * g + r][w * 32 + 1 * 16 + c] = yB;
    }
    __syncthreads();

    // ---- 512B-contiguous stores: 2 passes x (8 ch-rows x 32 lanes x float4) ----
    #pragma unroll
    for (int p = 0; p < 2; ++p) {
        const int ch = p * 8 + (tid >> 5);
        const int l5 = tid & 31;
        const int pp = pbase + 4 * l5;
        const int ob = (pp >= HWD) ? 1 : 0;
        const float4 vv = *(const float4*)&sY[ch][4 * l5];
        *(float4*)(out + ((size_t)(ob * 16 + ch)) * HWD + (pp - ob * HWD)) = vv;
    }
}

extern "C" void kernel_launch(void* const* d_in, const int* in_sizes, int n_in,
                              void* d_out, int out_size, void* d_ws, size_t ws_size,
                              hipStream_t stream)
{
    const float* x    = (const float*)d_in[0];
    const float* k1   = (const float*)d_in[1];
    const float* k2   = (const float*)d_in[2];
    const float* bias = (const float*)d_in[3];
    float* out = (float*)d_out;
    _Float16* tbl = (_Float16*)d_ws;     // 12 KB, fragment-major

    smorph_build_tables<<<(4 * 3 * 4 * 16 * 8 + 255) / 256, 256, 0, stream>>>(k1, k2, tbl);
    smorph_mfma9<<<(NPOS + 127) / 128, 256, 0, stream>>>(x, tbl, bias, out);
}

// Round 15
// 17.217 us; speedup vs baseline: 1.0292x; 1.0292x over previous
//
#include <hip/hip_runtime.h>

#define HWD    48400          // 220*220
#define PATCHD 75
#define NPOS   96800          // 2 * HWD
#define LOG2E  1.44269504088896340736f

typedef __attribute__((ext_vector_type(8))) _Float16 f16x8;
typedef __attribute__((ext_vector_type(2))) __fp16   h16x2;   // cvt_pkrtz return type
typedef __attribute__((ext_vector_type(4))) float    f32x4;

union U2 { h16x2 h; unsigned u; };
union UF { unsigned u[4]; f16x8 v; };

// ---------------------------------------------------------------------------
// SINGLE-DISPATCH fused kernel.
// Preamble: fragment-major f16 tables built cooperatively into LDS (12 KB):
//   sT[((t*4 + g)*16 + c)*8 + j],  t = role*3 + s,  k = 32s + 8g + j
//   role 0 = exp(k1), 1 = k1*exp(k1), 2 = exp(k2), 3 = k2*exp(k2); k>=75 -> 0
// Body: round-13 structure — each wave owns two adjacent 16-pos MFMA tiles,
// all x loads issued up front (clamped k; zero table rows annihilate pad),
// E=exp2(t), R=exp2(-t), 36 MFMAs, direct 64B-segment stores.
// ---------------------------------------------------------------------------
__global__ __launch_bounds__(256, 3)
void smorph_fused(const float* __restrict__ x,
                  const float* __restrict__ k1,
                  const float* __restrict__ k2,
                  const float* __restrict__ bias,
                  float* __restrict__ out)
{
    __shared__ __align__(16) _Float16 sT[6144];      // 12 KB fragment-major tables

    const int tid = (int)threadIdx.x;

    // ---- cooperative table build: 24 entries/thread ----
    for (int i = tid; i < 6144; i += 256) {
        const int j  = i & 7;
        const int cc = (i >> 3) & 15;
        const int gg = (i >> 7) & 3;
        const int t  = i >> 9;        // 0..11 = role*3 + s
        const int s  = t % 3;
        const int r  = t / 3;
        const int k  = 32 * s + 8 * gg + j;
        float val = 0.f;
        if (k < PATCHD) {
            const float* kw = (r < 2) ? k1 : k2;
            const float wv = kw[k * 16 + cc];
            const float e  = __expf(wv);
            val = (r & 1) ? (wv * e) : e;
        }
        sT[i] = (_Float16)val;
    }
    __syncthreads();

    const int l = tid & 63;
    const int w = tid >> 6;
    const int g = l >> 4;           // k-subgroup 0..3
    const int c = l & 15;           // channel lane (A-op) / position lane (B-op, D)

    int bb = (int)blockIdx.x * 128;
    if (bb > NPOS - 128) bb = NPOS - 128;    // clamp: duplicate identical stores
    const int pA = bb + w * 32;
    const int pB = pA + 16;
    const int bA = (pA >= HWD) ? 1 : 0;      // HWD % 16 == 0: tiles never straddle
    const int bB = (pB >= HWD) ? 1 : 0;
    const int hwA = pA - bA * HWD;
    const int hwB = pB - bB * HWD;
    const float* xbA = x + (size_t)bA * PATCHD * HWD + hwA + c;
    const float* xbB = x + (size_t)bB * PATCHD * HWD + hwB + c;

    // ---- table fragments from LDS: 12 conflict-free ds_read_b128 ----
    const f16x8* tf = (const f16x8*)sT;
    const int fbase = g * 16 + c;
    f16x8 Tf[12];
    #pragma unroll
    for (int t = 0; t < 12; ++t) Tf[t] = tf[t * 64 + fbase];

    // ---- all x loads up front: 2 tiles x 24 ----
    float xvA[24], xvB[24];
    #pragma unroll
    for (int s = 0; s < 3; ++s)
        #pragma unroll
        for (int j = 0; j < 8; ++j) {
            int k = 32 * s + 8 * g + j;
            k = (k > PATCHD - 1) ? (PATCHD - 1) : k;
            xvA[s * 8 + j] = xbA[(size_t)k * HWD];
            xvB[s * 8 + j] = xbB[(size_t)k * HWD];
        }

    f32x4 aN1A = {0.f,0.f,0.f,0.f}, aD1A = {0.f,0.f,0.f,0.f};
    f32x4 aN2A = {0.f,0.f,0.f,0.f}, aD2A = {0.f,0.f,0.f,0.f};
    f32x4 aN1B = {0.f,0.f,0.f,0.f}, aD1B = {0.f,0.f,0.f,0.f};
    f32x4 aN2B = {0.f,0.f,0.f,0.f}, aD2B = {0.f,0.f,0.f,0.f};

    #define COMP(src, aN1, aD1, aN2, aD2)                                     \
        _Pragma("unroll")                                                     \
        for (int s = 0; s < 3; ++s) {                                         \
            float E[8], R[8];                                                 \
            _Pragma("unroll")                                                 \
            for (int j = 0; j < 8; ++j) {                                     \
                const float t_ = (src)[s * 8 + j] * LOG2E;                    \
                E[j] = __builtin_amdgcn_exp2f(t_);                            \
                R[j] = __builtin_amdgcn_exp2f(-t_);                           \
            }                                                                 \
            UF fEx, fE, fRx, fR;                                              \
            _Pragma("unroll")                                                 \
            for (int jp = 0; jp < 4; ++jp) {                                  \
                const float x0 = (src)[s * 8 + 2 * jp];                       \
                const float x1 = (src)[s * 8 + 2 * jp + 1];                   \
                U2 q;                                                         \
                q.h = __builtin_amdgcn_cvt_pkrtz(E[2*jp] * x0,  E[2*jp+1] * x1);  fEx.u[jp] = q.u; \
                q.h = __builtin_amdgcn_cvt_pkrtz(E[2*jp],       E[2*jp+1]);       fE.u[jp]  = q.u; \
                q.h = __builtin_amdgcn_cvt_pkrtz(-R[2*jp] * x0, -R[2*jp+1] * x1); fRx.u[jp] = q.u; \
                q.h = __builtin_amdgcn_cvt_pkrtz(R[2*jp],       R[2*jp+1]);       fR.u[jp]  = q.u; \
            }                                                                 \
            aN1 = __builtin_amdgcn_mfma_f32_16x16x32_f16(Tf[0 + s], fEx.v, aN1, 0, 0, 0); \
            aN1 = __builtin_amdgcn_mfma_f32_16x16x32_f16(Tf[3 + s], fE.v,  aN1, 0, 0, 0); \
            aD1 = __builtin_amdgcn_mfma_f32_16x16x32_f16(Tf[0 + s], fE.v,  aD1, 0, 0, 0); \
            aN2 = __builtin_amdgcn_mfma_f32_16x16x32_f16(Tf[6 + s], fRx.v, aN2, 0, 0, 0); \
            aN2 = __builtin_amdgcn_mfma_f32_16x16x32_f16(Tf[9 + s], fR.v,  aN2, 0, 0, 0); \
            aD2 = __builtin_amdgcn_mfma_f32_16x16x32_f16(Tf[6 + s], fR.v,  aD2, 0, 0, 0); \
        }

    COMP(xvA, aN1A, aD1A, aN2A, aD2A)      // B's loads drain underneath
    COMP(xvB, aN1B, aD1B, aN2B, aD2B)
    #undef COMP

    // ---- epilogue: y = num1/den1 + num2/den2 + bias ----
    const float4 bsv = *(const float4*)(bias + 4 * g);
    float* obA = out + ((size_t)(bA * 16 + 4 * g)) * HWD + hwA + c;
    float* obB = out + ((size_t)(bB * 16 + 4 * g)) * HWD + hwB + c;
    #pragma unroll
    for (int r = 0; r < 4; ++r) {
        const float bsr = (r == 0) ? bsv.x : (r == 1) ? bsv.y : (r == 2) ? bsv.z : bsv.w;
        obA[(size_t)r * HWD] = aN1A[r] * __builtin_amdgcn_rcpf(aD1A[r])
                             + aN2A[r] * __builtin_amdgcn_rcpf(aD2A[r]) + bsr;
        obB[(size_t)r * HWD] = aN1B[r] * __builtin_amdgcn_rcpf(aD1B[r])
                             + aN2B[r] * __builtin_amdgcn_rcpf(aD2B[r]) + bsr;
    }
}

extern "C" void kernel_launch(void* const* d_in, const int* in_sizes, int n_in,
                              void* d_out, int out_size, void* d_ws, size_t ws_size,
                              hipStream_t stream)
{
    const float* x    = (const float*)d_in[0];
    const float* k1   = (const float*)d_in[1];
    const float* k2   = (const float*)d_in[2];
    const float* bias = (const float*)d_in[3];
    float* out = (float*)d_out;

    smorph_fused<<<(NPOS + 127) / 128, 256, 0, stream>>>(x, k1, k2, bias, out);
}